// Round 1
// baseline (565.440 us; speedup 1.0000x reference)
//
#include <hip/hip_runtime.h>
#include <hip/hip_bf16.h>

#define BATCH 32768
#define IN_DIM 64
#define NUM_CLASSES 4096

typedef short bf16x8 __attribute__((ext_vector_type(8)));   // 8 bf16 = 4 VGPRs
typedef float f32x4 __attribute__((ext_vector_type(4)));    // MFMA 16x16 accumulator

// Convert fp32 rows (length 64) to bf16 and emit per-row sum of squares (fp32).
// One float4 (4 elements) per thread; a row = 16 consecutive threads.
__global__ void convert_rows(const float* __restrict__ src,
                             unsigned short* __restrict__ dst,
                             float* __restrict__ sq) {
    int t = blockIdx.x * blockDim.x + threadIdx.x;
    float4 v = ((const float4*)src)[t];

    __hip_bfloat16 h0 = __float2bfloat16(v.x);
    __hip_bfloat16 h1 = __float2bfloat16(v.y);
    __hip_bfloat16 h2 = __float2bfloat16(v.z);
    __hip_bfloat16 h3 = __float2bfloat16(v.w);
    ushort4 o;
    o.x = __builtin_bit_cast(unsigned short, h0);
    o.y = __builtin_bit_cast(unsigned short, h1);
    o.z = __builtin_bit_cast(unsigned short, h2);
    o.w = __builtin_bit_cast(unsigned short, h3);
    ((ushort4*)dst)[t] = o;

    // fp32 sum of squares (exact path for the -x.x term)
    float s = v.x * v.x + v.y * v.y + v.z * v.z + v.w * v.w;
    s += __shfl_xor(s, 1, 16);
    s += __shfl_xor(s, 2, 16);
    s += __shfl_xor(s, 4, 16);
    s += __shfl_xor(s, 8, 16);
    if ((threadIdx.x & 15) == 0) sq[t >> 4] = s;
}

// logits[m][n] = 2*dot(x[m], w[n]) - xsq[m] - wsq[n]
// Block tile 128x128, 4 waves in 2x2, each wave 64x64 via 4x4 frags of 16x16x32.
// A/B fragments loaded directly from global in native MFMA operand layout:
// row-major with IN_DIM=64 means lane reads 16 contiguous bytes at
// base + (frag_row + lane&15)*64 + (lane>>4)*8 + kstep*32.
__global__ __launch_bounds__(256) void rbf_gemm(
    const unsigned short* __restrict__ xb,   // [BATCH][64] bf16
    const unsigned short* __restrict__ wb,   // [NUM_CLASSES][64] bf16
    const float* __restrict__ xsq,           // [BATCH]
    const float* __restrict__ wsq,           // [NUM_CLASSES]
    float* __restrict__ out)                 // [BATCH][NUM_CLASSES]
{
    const int bid    = blockIdx.x;
    const int tile_n = bid & 31;     // 4096/128 = 32 n-tiles (fast-varying: w L2 reuse)
    const int tile_m = bid >> 5;     // 32768/128 = 256 m-tiles
    const int lane   = threadIdx.x & 63;
    const int wave   = threadIdx.x >> 6;
    const int wm     = wave >> 1;
    const int wn     = wave & 1;
    const int m0     = tile_m * 128 + wm * 64;
    const int n0     = tile_n * 128 + wn * 64;
    const int r      = lane & 15;
    const int quad   = lane >> 4;

    const unsigned short* arow = xb + (size_t)(m0 + r) * IN_DIM + quad * 8;
    const unsigned short* brow = wb + (size_t)(n0 + r) * IN_DIM + quad * 8;

    bf16x8 a[4][2], b[4][2];
#pragma unroll
    for (int i = 0; i < 4; ++i) {
#pragma unroll
        for (int s = 0; s < 2; ++s) {
            a[i][s] = *(const bf16x8*)(arow + i * 16 * IN_DIM + s * 32);
            b[i][s] = *(const bf16x8*)(brow + i * 16 * IN_DIM + s * 32);
        }
    }

    f32x4 acc[4][4];
#pragma unroll
    for (int i = 0; i < 4; ++i)
#pragma unroll
        for (int j = 0; j < 4; ++j)
            acc[i][j] = (f32x4)0.0f;

#pragma unroll
    for (int s = 0; s < 2; ++s)
#pragma unroll
        for (int i = 0; i < 4; ++i)
#pragma unroll
            for (int j = 0; j < 4; ++j)
                acc[i][j] = __builtin_amdgcn_mfma_f32_16x16x32_bf16(
                    a[i][s], b[j][s], acc[i][j], 0, 0, 0);

    // Epilogue: C/D layout col = lane&15, row = quad*4 + reg
    float wsq_r[4];
#pragma unroll
    for (int j = 0; j < 4; ++j) wsq_r[j] = wsq[n0 + j * 16 + r];

#pragma unroll
    for (int i = 0; i < 4; ++i) {
#pragma unroll
        for (int reg = 0; reg < 4; ++reg) {
            const int m = m0 + i * 16 + quad * 4 + reg;
            const float xs = xsq[m];
            float* obase = out + (size_t)m * NUM_CLASSES + n0 + r;
#pragma unroll
            for (int j = 0; j < 4; ++j)
                obase[j * 16] = 2.0f * acc[i][j][reg] - xs - wsq_r[j];
        }
    }
}

extern "C" void kernel_launch(void* const* d_in, const int* in_sizes, int n_in,
                              void* d_out, int out_size, void* d_ws, size_t ws_size,
                              hipStream_t stream) {
    const float* x = (const float*)d_in[0];   // [32768, 64] fp32
    const float* w = (const float*)d_in[1];   // [4096, 64] fp32, values +/-1
    float* out = (float*)d_out;               // [32768, 4096] fp32

    // Workspace layout (~4.66 MiB total):
    char* ws = (char*)d_ws;
    unsigned short* xb = (unsigned short*)ws;                                   // 4 MiB
    unsigned short* wb = (unsigned short*)(ws + (size_t)BATCH * IN_DIM * 2);    // 512 KiB
    float* xsq = (float*)(ws + (size_t)BATCH * IN_DIM * 2
                             + (size_t)NUM_CLASSES * IN_DIM * 2);               // 128 KiB
    float* wsq = xsq + BATCH;                                                   // 16 KiB

    convert_rows<<<(BATCH * IN_DIM / 4) / 256, 256, 0, stream>>>(x, xb, xsq);
    convert_rows<<<(NUM_CLASSES * IN_DIM / 4) / 256, 256, 0, stream>>>(w, wb, wsq);

    const int grid = (BATCH / 128) * (NUM_CLASSES / 128);  // 256 * 32 = 8192
    rbf_gemm<<<grid, 256, 0, stream>>>(xb, wb, xsq, wsq, out);
}